// Round 1
// baseline (2867.720 us; speedup 1.0000x reference)
//
#include <hip/hip_runtime.h>
#include <math.h>

// Problem constants
#define A_N    2000
#define P_N    20000
#define E_N    200000
#define MUL0   128
#define MUL1   64
#define DIM    320     // MUL0 + 3*MUL1
#define NBASIS 10
#define FC_HID 100
#define WNUM   384     // 128+128+64+64
#define MID0   192     // MUL0 + MUL1
#define RDIM   768     // 128 + 64 + 384 + 192

// scales
#define RS10   0.31622776601683794f   // 1/sqrt(10)
#define RS100  0.1f                   // 1/sqrt(100)
#define RS128  0.08838834764831845f   // 1/sqrt(128)
#define RS64   0.125f                 // 1/sqrt(64)
#define RS192  0.07216878364870323f   // 1/sqrt(192)
#define RS3    0.5773502691896258f    // 1/sqrt(3)
#define RSNEI  0.31622776601683794f   // 1/sqrt(10) neighbors

// ---------------------------------------------------------------------------
// Kernel 1: sender transform. s0[a][j] = (s_in[a,:128] @ lin1_w0)[j]/sqrt(128)
//           s1[a][3v+m] = sum_u s_in[a,128+3u+m]*lin1_w1[u][v] / 8
// block = 320 threads, one sender per block (A=2000 blocks, tiny kernel)
// ---------------------------------------------------------------------------
__global__ __launch_bounds__(320) void sender_kernel(
    const float* __restrict__ sender_input, const float* __restrict__ sender_attr,
    const float* __restrict__ lin1_w0, const float* __restrict__ lin1_w1,
    float* __restrict__ s0, float* __restrict__ s1)
{
    __shared__ float sin_s[DIM];
    const int a = blockIdx.x;
    const int t = threadIdx.x;
    const float attr = sender_attr[a];
    sin_s[t] = sender_input[(size_t)a * DIM + t] * attr;
    __syncthreads();
    if (t < MUL0) {
        float acc = 0.f;
        for (int u = 0; u < MUL0; ++u)
            acc = fmaf(sin_s[u], lin1_w0[u * MUL0 + t], acc);
        s0[(size_t)a * MUL0 + t] = acc * RS128;
    } else {
        const int idx = t - MUL0;          // 0..191
        const int v = idx / 3, m = idx - 3 * v;
        float acc = 0.f;
        for (int u = 0; u < MUL1; ++u)
            acc = fmaf(sin_s[MUL0 + 3 * u + m], lin1_w1[u * MUL1 + v], acc);
        s1[(size_t)a * 192 + idx] = acc * RS64;
    }
}

// ---------------------------------------------------------------------------
// Kernel 2: edge path. 256 threads = 4 waves, 8 edges/wave -> 32 edges/block.
// h = silu(es @ fc_w1 / sqrt(10));  weight = h @ fc_w2 / 10 (in registers);
// epilogue: form edge_feat (768) and atomicAdd into r[dst].
// Lane owns weight columns {lane + 64*c : c=0..5}.
// ---------------------------------------------------------------------------
__global__ __launch_bounds__(256) void edge_kernel(
    const float* __restrict__ edge_scalars, const float* __restrict__ edge_attr,
    const int*   __restrict__ edge_src,     const int*   __restrict__ edge_dst,
    const float* __restrict__ fc_w1,        const float* __restrict__ fc_w2,
    const float* __restrict__ s0,           const float* __restrict__ s1,
    float* __restrict__ r)
{
    __shared__ float fc1s[NBASIS * FC_HID];   // 1000 f32  (4 KB)
    __shared__ float es_s[32 * NBASIS];       // 320       (1.3 KB)
    __shared__ float h_s[32 * FC_HID];        // 3200      (12.8 KB)
    __shared__ float w2s[20 * WNUM];          // 7680      (30.7 KB)

    const int tid  = threadIdx.x;
    const int wave = tid >> 6;
    const int lane = tid & 63;
    const int eblock = blockIdx.x * 32;

    for (int i = tid; i < NBASIS * FC_HID; i += 256) fc1s[i] = fc_w1[i];
    for (int i = tid; i < 32 * NBASIS; i += 256)
        es_s[i] = edge_scalars[(size_t)eblock * NBASIS + i];
    __syncthreads();

    // h for 32 edges (3200 values over 256 threads)
    for (int idx = tid; idx < 32 * FC_HID; idx += 256) {
        const int e = idx / FC_HID, k = idx - e * FC_HID;
        float x = 0.f;
        #pragma unroll
        for (int i = 0; i < NBASIS; ++i)
            x = fmaf(es_s[e * NBASIS + i], fc1s[i * FC_HID + k], x);
        x *= RS10;
        h_s[idx] = x / (1.f + __expf(-x));    // silu
    }

    float acc[8][6];
    #pragma unroll
    for (int e = 0; e < 8; ++e)
        #pragma unroll
        for (int c = 0; c < 6; ++c) acc[e][c] = 0.f;

    for (int kk = 0; kk < FC_HID; kk += 20) {
        __syncthreads();  // h ready (first iter) / previous w2s chunk consumed
        for (int i = tid; i < 20 * WNUM; i += 256)
            w2s[i] = fc_w2[kk * WNUM + i];
        __syncthreads();
        for (int k = 0; k < 20; ++k) {
            float w[6];
            #pragma unroll
            for (int c = 0; c < 6; ++c) w[c] = w2s[k * WNUM + c * 64 + lane];
            #pragma unroll
            for (int e = 0; e < 8; ++e) {
                const float hv = h_s[(wave * 8 + e) * FC_HID + kk + k];
                #pragma unroll
                for (int c = 0; c < 6; ++c) acc[e][c] = fmaf(hv, w[c], acc[e][c]);
            }
        }
    }

    // epilogue: per edge, per lane: 12 atomicAdds (768 floats per edge total)
    const int my_e = eblock + wave * 8;
    #pragma unroll
    for (int e = 0; e < 8; ++e) {
        const int eg  = my_e + e;
        const int src = edge_src[eg];
        const int dst = edge_dst[eg];
        const float sh0  = edge_attr[eg * 4 + 0];
        const float sh1x = edge_attr[eg * 4 + 1];
        const float sh1y = edge_attr[eg * 4 + 2];
        const float sh1z = edge_attr[eg * 4 + 3];

        const float g0a = s0[(size_t)src * MUL0 + lane];
        const float g0b = s0[(size_t)src * MUL0 + 64 + lane];
        const float g1x = s1[(size_t)src * 192 + 3 * lane + 0];
        const float g1y = s1[(size_t)src * 192 + 3 * lane + 1];
        const float g1z = s1[(size_t)src * 192 + 3 * lane + 2];

        const float w0a = acc[e][0] * RS100, w0b = acc[e][1] * RS100;
        const float w1a = acc[e][2] * RS100, w1b = acc[e][3] * RS100;
        const float w2v = acc[e][4] * RS100, w3v = acc[e][5] * RS100;

        float* rr = r + (size_t)dst * RDIM;
        // out0a: cols 0..127
        atomicAdd(rr + lane,       w0a * g0a * sh0);
        atomicAdd(rr + 64 + lane,  w0b * g0b * sh0);
        // out0b: cols 128..191
        const float dotg = fmaf(g1x, sh1x, fmaf(g1y, sh1y, g1z * sh1z)) * RS3;
        atomicAdd(rr + 128 + lane, w3v * dotg);
        // out1a: cols 192 + 3u + m (u=lane and u=64+lane)
        const float p1a = w1a * g0a, p1b = w1b * g0b;
        atomicAdd(rr + 192 + 3 * lane + 0, p1a * sh1x);
        atomicAdd(rr + 192 + 3 * lane + 1, p1a * sh1y);
        atomicAdd(rr + 192 + 3 * lane + 2, p1a * sh1z);
        atomicAdd(rr + 384 + 3 * lane + 0, p1b * sh1x);
        atomicAdd(rr + 384 + 3 * lane + 1, p1b * sh1y);
        atomicAdd(rr + 384 + 3 * lane + 2, p1b * sh1z);
        // out1b: cols 576 + 3v + m
        const float q = w2v * sh0;
        atomicAdd(rr + 576 + 3 * lane + 0, q * g1x);
        atomicAdd(rr + 576 + 3 * lane + 1, q * g1y);
        atomicAdd(rr + 576 + 3 * lane + 2, q * g1z);
    }
}

// ---------------------------------------------------------------------------
// Kernel 3: receiver finish. 320 threads, 8 receivers per block.
// r (scaled) -> conv0/conv1/angle;  receiver_input -> sc0/sc1;
// out = cos(angle)*sc + sin(angle)*conv
// ---------------------------------------------------------------------------
__global__ __launch_bounds__(320) void recv_kernel(
    const float* __restrict__ receiver_input, const float* __restrict__ receiver_attr,
    const float* __restrict__ sc_w0,  const float* __restrict__ sc_w1,
    const float* __restrict__ lin2_w0, const float* __restrict__ lin2_w1,
    const float* __restrict__ lin3_w,
    const float* __restrict__ r, float* __restrict__ out)
{
    __shared__ float rin_s[8 * DIM];    // 2560 f32
    __shared__ float rr_s[8 * RDIM];    // 6144 f32
    __shared__ float cos_s[8], sin_s[8];

    const int tid = threadIdx.x;
    const int pbase = blockIdx.x * 8;

    for (int i = tid; i < 8 * DIM; i += 320) {
        const int p = i / DIM;
        rin_s[i] = receiver_input[(size_t)pbase * DIM + i] * receiver_attr[pbase + p];
    }
    for (int i = tid; i < 8 * RDIM; i += 320) {
        const int p = i / RDIM;
        rr_s[i] = r[(size_t)pbase * RDIM + i] * RSNEI * receiver_attr[pbase + p];
    }
    __syncthreads();

    // angle per receiver: 8 lanes per receiver, shuffle reduce
    if (tid < 64) {
        const int p = tid >> 3, i0 = tid & 7;
        float a = 0.f;
        for (int u = i0; u < MID0; u += 8)
            a = fmaf(rr_s[p * RDIM + u], lin3_w[u], a);
        a += __shfl_xor(a, 1);
        a += __shfl_xor(a, 2);
        a += __shfl_xor(a, 4);
        if (i0 == 0) {
            a *= 0.1f * RS192;
            cos_s[p] = __cosf(a);
            sin_s[p] = __sinf(a);
        }
    }
    __syncthreads();

    if (tid < MUL0) {
        const int j = tid;
        float asc[8], acv[8];
        #pragma unroll
        for (int p = 0; p < 8; ++p) { asc[p] = 0.f; acv[p] = 0.f; }
        for (int u = 0; u < MUL0; ++u) {
            const float w = sc_w0[u * MUL0 + j];
            #pragma unroll
            for (int p = 0; p < 8; ++p) asc[p] = fmaf(rin_s[p * DIM + u], w, asc[p]);
        }
        for (int u = 0; u < MID0; ++u) {
            const float w = lin2_w0[u * MUL0 + j];
            #pragma unroll
            for (int p = 0; p < 8; ++p) acv[p] = fmaf(rr_s[p * RDIM + u], w, acv[p]);
        }
        #pragma unroll
        for (int p = 0; p < 8; ++p)
            out[(size_t)(pbase + p) * DIM + j] =
                cos_s[p] * asc[p] * RS128 + sin_s[p] * acv[p] * RS192;
    } else {
        const int idx = tid - MUL0;            // 0..191
        const int v = idx / 3, m = idx - 3 * v;
        float asc[8], acv[8];
        #pragma unroll
        for (int p = 0; p < 8; ++p) { asc[p] = 0.f; acv[p] = 0.f; }
        for (int u = 0; u < MUL1; ++u) {
            const float w = sc_w1[u * MUL1 + v];
            #pragma unroll
            for (int p = 0; p < 8; ++p)
                asc[p] = fmaf(rin_s[p * DIM + MUL0 + 3 * u + m], w, asc[p]);
        }
        for (int u = 0; u < MID0; ++u) {
            const float w = lin2_w1[u * MUL1 + v];
            #pragma unroll
            for (int p = 0; p < 8; ++p)
                acv[p] = fmaf(rr_s[p * RDIM + 192 + 3 * u + m], w, acv[p]);
        }
        #pragma unroll
        for (int p = 0; p < 8; ++p)
            out[(size_t)(pbase + p) * DIM + MUL0 + idx] =
                cos_s[p] * asc[p] * RS64 + sin_s[p] * acv[p] * RS192;
    }
}

// ---------------------------------------------------------------------------
extern "C" void kernel_launch(void* const* d_in, const int* in_sizes, int n_in,
                              void* d_out, int out_size, void* d_ws, size_t ws_size,
                              hipStream_t stream)
{
    const float* sender_input   = (const float*)d_in[0];
    const float* sender_attr    = (const float*)d_in[1];
    const float* receiver_input = (const float*)d_in[2];
    const float* receiver_attr  = (const float*)d_in[3];
    const int*   edge_src       = (const int*)  d_in[4];
    const int*   edge_dst       = (const int*)  d_in[5];
    const float* edge_attr      = (const float*)d_in[6];
    const float* edge_scalars   = (const float*)d_in[7];
    const float* fc_w1          = (const float*)d_in[8];
    const float* fc_w2          = (const float*)d_in[9];
    const float* lin1_w0        = (const float*)d_in[10];
    const float* lin1_w1        = (const float*)d_in[11];
    const float* sc_w0          = (const float*)d_in[12];
    const float* sc_w1          = (const float*)d_in[13];
    const float* lin2_w0        = (const float*)d_in[14];
    const float* lin2_w1        = (const float*)d_in[15];
    const float* lin3_w         = (const float*)d_in[16];
    float* out = (float*)d_out;

    // workspace layout (f32): s0 [A,128] | s1 [A,192] | r [P,768]  = 64 MB
    float* s0 = (float*)d_ws;
    float* s1 = s0 + (size_t)A_N * MUL0;
    float* r  = s1 + (size_t)A_N * 192;

    sender_kernel<<<A_N, 320, 0, stream>>>(sender_input, sender_attr,
                                           lin1_w0, lin1_w1, s0, s1);
    hipMemsetAsync(r, 0, (size_t)P_N * RDIM * sizeof(float), stream);
    edge_kernel<<<E_N / 32, 256, 0, stream>>>(edge_scalars, edge_attr,
                                              edge_src, edge_dst,
                                              fc_w1, fc_w2, s0, s1, r);
    recv_kernel<<<P_N / 8, 320, 0, stream>>>(receiver_input, receiver_attr,
                                             sc_w0, sc_w1, lin2_w0, lin2_w1,
                                             lin3_w, r, out);
}